// Round 7
// baseline (859.443 us; speedup 1.0000x reference)
//
#include <hip/hip_runtime.h>

#define D 128
#define BM 128
#define NREL 8
#define SCAN_BLOCKS 782
#define MPAD (SCAN_BLOCKS * 1024)  // 800768 >= 8*N+1

typedef __attribute__((ext_vector_type(8))) short short8;
typedef __attribute__((ext_vector_type(4))) float f32x4;

typedef void __attribute__((address_space(3))) lvoid_t;

__device__ inline unsigned short f2bf(float f) {
  unsigned u = __builtin_bit_cast(unsigned, f);
  u += 0x7FFFu + ((u >> 16) & 1u);
  return (unsigned short)(u >> 16);
}

// packed 2xbf16 LDS atomic add; no memory clobber (ordering handled by an
// explicit lgkmcnt(0)+sched_barrier before the post-gather __syncthreads).
__device__ inline void ds_pk_add(void* lptr, unsigned data) {
  asm volatile("ds_pk_add_bf16 %0, %1" ::"v"((lvoid_t*)lptr), "v"(data));
}

// emb f32 -> xb bf16, compact [N][128]
__global__ __launch_bounds__(256) void cvt_x(const float* __restrict__ x,
                                             unsigned short* __restrict__ dst,
                                             long total /* = N*32 float4 */) {
  long i = (long)blockIdx.x * 256 + threadIdx.x;
  if (i >= total) return;
  float4 v = reinterpret_cast<const float4*>(x)[i];
  unsigned lo = (unsigned)f2bf(v.x) | ((unsigned)f2bf(v.y) << 16);
  unsigned hi = (unsigned)f2bf(v.z) | ((unsigned)f2bf(v.w) << 16);
  reinterpret_cast<uint2*>(dst)[i] = make_uint2(lo, hi);
}

// Btr[layer][r][c][k] bf16 (plain, no swizzle): r<8 -> W[r][k][c], r=8 -> SL[k][c]
__global__ __launch_bounds__(256) void wcvt(const float* __restrict__ W1,
                                            const float* __restrict__ SL1,
                                            const float* __restrict__ W2,
                                            const float* __restrict__ SL2,
                                            unsigned short* __restrict__ Btr) {
  int idx = blockIdx.x * 256 + threadIdx.x;
  if (idx >= 2 * 9 * D * D) return;
  int l = idx >= 9 * D * D;
  int t = idx - l * 9 * D * D;
  int r = t >> 14;
  int rem = t & 16383;
  int c = rem >> 7;
  int k = rem & 127;
  const float* W = l ? W2 : W1;
  const float* SL = l ? SL2 : SL1;
  float v = (r < NREL) ? W[((r * D) + k) * D + c] : SL[k * D + c];
  Btr[idx] = f2bf(v);
}

__global__ __launch_bounds__(256) void hist_kernel(const int* __restrict__ dst,
                                                   const int* __restrict__ rel,
                                                   int* __restrict__ counts,
                                                   int E) {
  int e = blockIdx.x * 256 + threadIdx.x;
  if (e >= E) return;
  atomicAdd(&counts[(dst[e] << 3) | rel[e]], 1);
}

__global__ __launch_bounds__(256) void scan1(const int* __restrict__ in,
                                             int* __restrict__ out,
                                             int* __restrict__ bsum) {
  __shared__ int tmp[256];
  int t = threadIdx.x;
  long base = (long)blockIdx.x * 1024 + t * 4;
  int v[4];
  int s = 0;
#pragma unroll
  for (int j = 0; j < 4; ++j) {
    v[j] = in[base + j];
    s += v[j];
  }
  tmp[t] = s;
  __syncthreads();
  for (int off = 1; off < 256; off <<= 1) {
    int x = (t >= off) ? tmp[t - off] : 0;
    __syncthreads();
    tmp[t] += x;
    __syncthreads();
  }
  int run = tmp[t] - s;
  if (t == 255) bsum[blockIdx.x] = tmp[255];
#pragma unroll
  for (int j = 0; j < 4; ++j) {
    out[base + j] = run;
    run += v[j];
  }
}

__global__ __launch_bounds__(1024) void scan_top(int* __restrict__ bsum, int nb) {
  __shared__ int tmp[1024];
  int t = threadIdx.x;
  int v = (t < nb) ? bsum[t] : 0;
  tmp[t] = v;
  __syncthreads();
  for (int off = 1; off < 1024; off <<= 1) {
    int x = (t >= off) ? tmp[t - off] : 0;
    __syncthreads();
    tmp[t] += x;
    __syncthreads();
  }
  if (t < nb) bsum[t] = tmp[t] - v;
}

__global__ __launch_bounds__(256) void scan_add(int* __restrict__ starts,
                                                int* __restrict__ cursor,
                                                const int* __restrict__ bsum) {
  long base = (long)blockIdx.x * 1024 + threadIdx.x * 4;
  int add = bsum[blockIdx.x];
#pragma unroll
  for (int j = 0; j < 4; ++j) {
    int v = starts[base + j] + add;
    starts[base + j] = v;
    cursor[base + j] = v;
  }
}

__global__ __launch_bounds__(256) void reorder(const int* __restrict__ src,
                                               const int* __restrict__ dst,
                                               const int* __restrict__ rel,
                                               int* __restrict__ cursor,
                                               int2* __restrict__ es, int E) {
  int e = blockIdx.x * 256 + threadIdx.x;
  if (e >= E) return;
  int key = (dst[e] << 3) | rel[e];
  int pos = atomicAdd(&cursor[key], 1);
  es[pos] = make_int2(src[e], key);
}

// Fused RGCN layer. Per 128-row block: for each K-half (64), ONE gather pass
// over the block's contiguous (dst,rel)-sorted edge range accumulates x[src]
// into 8 relation A-tiles (LDS, bf16, ds_pk_add), then 9 MFMA phases
// (r=0..7 A from LDS, r=8 self-loop A from global xb; B from global Btr).
// Tile stride: 128 rows x 64 k x 2B = 16384 B (round-6 bug: was 8192).
__global__ __launch_bounds__(256) void fused_layer(
    const unsigned short* __restrict__ xb, const int* __restrict__ starts,
    const int2* __restrict__ es, const unsigned short* __restrict__ Btr,
    const float* __restrict__ bias, unsigned short* __restrict__ xout_b,
    float* __restrict__ outf, int N) {
  extern __shared__ char tiles[];  // 8 x 16384 B = 131072 B, XOR-swizzled

  const int tid = threadIdx.x;
  const int wave = tid >> 6, lane = tid & 63;
  const int wm = wave >> 1, wn = wave & 1;
  const int l15 = lane & 15, lq = lane >> 4;
  const int row0 = blockIdx.x * BM;
  const int rowend = (row0 + BM < N) ? (row0 + BM) : N;
  const int eg = lane >> 2, cb = lane & 3;
  const char* xbB = reinterpret_cast<const char*>(xb);
  const char* BtrB = reinterpret_cast<const char*>(Btr);

  const int e0 = starts[row0 << 3];
  const int e1 = starts[rowend << 3];

  f32x4 acc[4][4];
#pragma unroll
  for (int m = 0; m < 4; ++m)
#pragma unroll
    for (int n = 0; n < 4; ++n)
#pragma unroll
      for (int q = 0; q < 4; ++q) acc[m][n][q] = 0.f;

  for (int half = 0; half < 2; ++half) {
    if (half) __syncthreads();  // previous MFMA reads done before overwrite
    // zero all 8 tiles (128 KB)
#pragma unroll
    for (int i = 0; i < 32; ++i)
      *reinterpret_cast<int4*>(tiles + i * 4096 + tid * 16) =
          make_int4(0, 0, 0, 0);
    __syncthreads();

    // gather: 16 edges/wave/iter, 4 lanes/edge, 32B (=16 k-elems) per lane.
    // Clamped (never guarded) loads + manual 2-stage prefetch: at 1 wave/SIMD
    // there is no TLP, so MLP must come from the pipeline.
    const int kbyte = half * 128 + cb * 32;
    const int ew = e0 + wave * 16 + eg;
    int2 sk;
    uint4 va, vb;
    {
      int ee = (ew < e1) ? ew : e0;
      sk = es[ee];
      const char* xp = xbB + (size_t)sk.x * 256 + kbyte;
      va = *reinterpret_cast<const uint4*>(xp);
      vb = *reinterpret_cast<const uint4*>(xp + 16);
    }
    for (int ebs = ew; ebs < e1; ebs += 64) {
      const bool curv = ebs < e1;
      int2 skc = sk;
      uint4 ca = va, cb4 = vb;
      {  // prefetch next batch (hoistable above the DS asm: no mem clobber)
        int en = ebs + 64;
        int ee = (en < e1) ? en : e0;
        sk = es[ee];
        const char* xp = xbB + (size_t)sk.x * 256 + kbyte;
        va = *reinterpret_cast<const uint4*>(xp);
        vb = *reinterpret_cast<const uint4*>(xp + 16);
      }
      if (curv) {
        int dstl = (skc.y >> 3) - row0;
        char* base = tiles + (skc.y & 7) * 16384 + dstl * 128;
        int sw = (dstl & 7) << 4;
        char* p0 = base + ((cb * 32) ^ sw);
        char* p1 = base + ((cb * 32 + 16) ^ sw);
        ds_pk_add(p0 + 0, ca.x);
        ds_pk_add(p0 + 4, ca.y);
        ds_pk_add(p0 + 8, ca.z);
        ds_pk_add(p0 + 12, ca.w);
        ds_pk_add(p1 + 0, cb4.x);
        ds_pk_add(p1 + 4, cb4.y);
        ds_pk_add(p1 + 8, cb4.z);
        ds_pk_add(p1 + 12, cb4.w);
      }
    }
    // drain the (compiler-invisible) DS atomics before the barrier
    asm volatile("s_waitcnt lgkmcnt(0)");
    __builtin_amdgcn_sched_barrier(0);
    __syncthreads();

    // 9 MFMA phases over K=64
    for (int r = 0; r < 9; ++r) {
      short8 af[4][2], bfr[4][2];
#pragma unroll
      for (int n = 0; n < 4; ++n) {
        int cc = wn * 64 + n * 16 + l15;
#pragma unroll
        for (int kq = 0; kq < 2; ++kq)
          bfr[n][kq] = *reinterpret_cast<const short8*>(
              BtrB + (((size_t)r * D + cc) * D + half * 64 + kq * 32 + lq * 8) * 2);
      }
      if (r < NREL) {
        const char* tb = tiles + r * 16384;
#pragma unroll
        for (int m = 0; m < 4; ++m) {
          int rr = wm * 64 + m * 16 + l15;
          int sw = (rr & 7) << 4;
#pragma unroll
          for (int kq = 0; kq < 2; ++kq)
            af[m][kq] = *reinterpret_cast<const short8*>(
                tb + rr * 128 + ((kq * 64 + lq * 16) ^ sw));
        }
      } else {
#pragma unroll
        for (int m = 0; m < 4; ++m) {
          int grow = row0 + wm * 64 + m * 16 + l15;
          if (grow >= N) grow = N - 1;
#pragma unroll
          for (int kq = 0; kq < 2; ++kq)
            af[m][kq] = *reinterpret_cast<const short8*>(
                xbB + (size_t)grow * 256 + half * 128 + kq * 64 + lq * 16);
        }
      }
#pragma unroll
      for (int m = 0; m < 4; ++m)
#pragma unroll
        for (int n = 0; n < 4; ++n) {
          acc[m][n] = __builtin_amdgcn_mfma_f32_16x16x32_bf16(
              af[m][0], bfr[n][0], acc[m][n], 0, 0, 0);
          acc[m][n] = __builtin_amdgcn_mfma_f32_16x16x32_bf16(
              af[m][1], bfr[n][1], acc[m][n], 0, 0, 0);
        }
    }
  }

  // epilogue: C/D layout col = lane&15, row = (lane>>4)*4 + reg
#pragma unroll
  for (int n = 0; n < 4; ++n) {
    int col = wn * 64 + n * 16 + l15;
    float bv = bias[col];
#pragma unroll
    for (int m = 0; m < 4; ++m) {
      int rbase = row0 + wm * 64 + m * 16 + lq * 4;
#pragma unroll
      for (int q = 0; q < 4; ++q) {
        int row = rbase + q;
        if (row < N) {
          float v = fmaxf(acc[m][n][q] + bv, 0.f);
          if (outf)
            outf[(size_t)row * D + col] = v;
          else
            xout_b[(size_t)row * D + col] = f2bf(v);
        }
      }
    }
  }
}

extern "C" void kernel_launch(void* const* d_in, const int* in_sizes, int n_in,
                              void* d_out, int out_size, void* d_ws, size_t ws_size,
                              hipStream_t stream) {
  const float* emb = (const float*)d_in[0];
  const float* W1 = (const float*)d_in[1];
  const float* SL1 = (const float*)d_in[2];
  const float* B1 = (const float*)d_in[3];
  const float* W2 = (const float*)d_in[4];
  const float* SL2 = (const float*)d_in[5];
  const float* B2 = (const float*)d_in[6];
  const int* eidx = (const int*)d_in[7];
  const int* etyp = (const int*)d_in[8];
  const int N = in_sizes[0] / D;
  const int E = in_sizes[8];
  const int* srcp = eidx;
  const int* dstp = eidx + E;
  float* outp = (float*)d_out;

  char* w = (char*)d_ws;
  unsigned short* xb0 = (unsigned short*)w;            // N*128 bf16
  unsigned short* xb1 = xb0 + (size_t)N * D;           // N*128 bf16
  unsigned short* Btr = xb1 + (size_t)N * D;           // 2*9*128*128 bf16
  int* counts = (int*)(Btr + 2 * 9 * D * D);           // MPAD ints
  int* starts = counts + MPAD;
  int* cursor = starts + MPAD;
  int* bsum = cursor + MPAD;                           // 1024 ints
  int2* es = (int2*)(bsum + 1024);                     // E int2 (src, key)

  const int eb = (E + 255) / 256;
  const int gm_blocks = (N + BM - 1) / BM;
  const int LDS_BYTES = 131072;

  hipFuncSetAttribute(reinterpret_cast<const void*>(fused_layer),
                      hipFuncAttributeMaxDynamicSharedMemorySize, LDS_BYTES);

  // preprocessing (graph structure shared by both layers)
  hipMemsetAsync(counts, 0, (size_t)MPAD * 4, stream);
  cvt_x<<<(int)(((long)N * 32 + 255) / 256), 256, 0, stream>>>(emb, xb0,
                                                               (long)N * 32);
  wcvt<<<(2 * 9 * D * D + 255) / 256, 256, 0, stream>>>(W1, SL1, W2, SL2, Btr);
  hist_kernel<<<eb, 256, 0, stream>>>(dstp, etyp, counts, E);
  scan1<<<SCAN_BLOCKS, 256, 0, stream>>>(counts, starts, bsum);
  scan_top<<<1, 1024, 0, stream>>>(bsum, SCAN_BLOCKS);
  scan_add<<<SCAN_BLOCKS, 256, 0, stream>>>(starts, cursor, bsum);
  reorder<<<eb, 256, 0, stream>>>(srcp, dstp, etyp, cursor, es, E);

  // layer 1: xb0 -> xb1 (bf16); layer 2: xb1 -> outp (f32)
  fused_layer<<<gm_blocks, 256, LDS_BYTES, stream>>>(xb0, starts, es, Btr, B1,
                                                     xb1, nullptr, N);
  fused_layer<<<gm_blocks, 256, LDS_BYTES, stream>>>(
      xb1, starts, es, Btr + 9 * D * D, B2, nullptr, outp, N);
}